// Round 3
// baseline (85.166 us; speedup 1.0000x reference)
//
#include <hip/hip_runtime.h>

#define MTOT 8192
#define NTOT 8192
#define DD   64

typedef __bf16 bf16x8 __attribute__((ext_vector_type(8)));
typedef float  f32x16 __attribute__((ext_vector_type(16)));
typedef unsigned short u16x4 __attribute__((ext_vector_type(4)));

// Round-to-nearest-even fp32 -> bf16 (top 16 bits), bit-trick.
__device__ __forceinline__ unsigned short bf16_rne(float v) {
    unsigned int u = __float_as_uint(v);
    u = u + 0x7FFFu + ((u >> 16) & 1u);
    return (unsigned short)(u >> 16);
}
__device__ __forceinline__ float bf16_to_f32(unsigned short h) {
    return __uint_as_float(((unsigned int)h) << 16);
}

#define MFMA(a, b, c) __builtin_amdgcn_mfma_f32_32x32x16_bf16((a), (b), (c), 0, 0, 0)

// 512 threads (8 waves), 128x128 tile, 2 blocks/CU -> 4 waves/SIMD.
// Split-bf16 MFMA (hh + hl + lh), operands SWAPPED (Y first) so the C/D
// reg-quad spans 4 consecutive output COLUMNS -> float4 stores.
__global__ __launch_bounds__(512, 4)
void rbf_mfma_kernel(const float* __restrict__ X,
                     const float* __restrict__ Y,
                     const float* __restrict__ gamma_p,
                     float* __restrict__ out)
{
    // Fragment-linear LDS: [tile(32 rows)][kstep(16 k)][lane][slot(8 bf16)]
    // lane = (row&31) | ((k>>3)&1)<<5 ; slot = k&7.
    __shared__ unsigned short XfH[4][4][64][8];
    __shared__ unsigned short XfL[4][4][64][8];
    __shared__ unsigned short YfH[4][4][64][8];
    __shared__ unsigned short YfL[4][4][64][8];
    __shared__ float xq[128];
    __shared__ float yq[128];

    const int t = threadIdx.x;
    const long row0 = (long)blockIdx.y * 128;
    const long col0 = (long)blockIdx.x * 128;

    // ---- stage + split fp32 -> (hi, lo) bf16 into fragment layout ----
    {
        const int k0   = (t & 15) * 4;          // k base
        const int ks   = k0 >> 4;               // k-step 0..3
        const int l32  = ((k0 >> 3) & 1) << 5;  // k-half -> lane bit 5
        const int slot = k0 & 4;                // 0 or 4
        #pragma unroll
        for (int i = 0; i < 4; ++i) {
            const int row  = (t >> 4) + i * 32;
            const int mt   = row >> 5;
            const int lane = (row & 31) | l32;
            const float4 vx = *reinterpret_cast<const float4*>(X + (row0 + row) * DD + k0);
            const float4 vy = *reinterpret_cast<const float4*>(Y + (col0 + row) * DD + k0);
            float xv[4] = {vx.x, vx.y, vx.z, vx.w};
            float yv[4] = {vy.x, vy.y, vy.z, vy.w};
            u16x4 xh, xl, yh, yl;
            #pragma unroll
            for (int e = 0; e < 4; ++e) {
                const unsigned short hx = bf16_rne(xv[e]);
                xh[e] = hx;
                xl[e] = bf16_rne(xv[e] - bf16_to_f32(hx));
                const unsigned short hy = bf16_rne(yv[e]);
                yh[e] = hy;
                yl[e] = bf16_rne(yv[e] - bf16_to_f32(hy));
            }
            *reinterpret_cast<u16x4*>(&XfH[mt][ks][lane][slot]) = xh;
            *reinterpret_cast<u16x4*>(&XfL[mt][ks][lane][slot]) = xl;
            *reinterpret_cast<u16x4*>(&YfH[mt][ks][lane][slot]) = yh;
            *reinterpret_cast<u16x4*>(&YfL[mt][ks][lane][slot]) = yl;
        }
    }

    // ---- row norms (threads 0..127 -> X, 128..255 -> Y; inputs L1-hot) ----
    if (t < 256) {
        const int r = t & 127;
        const float* p = (t < 128) ? (X + (row0 + r) * DD) : (Y + (col0 + r) * DD);
        float s0 = 0.f, s1 = 0.f, s2 = 0.f, s3 = 0.f;
        #pragma unroll
        for (int c = 0; c < 16; ++c) {
            const float4 v = reinterpret_cast<const float4*>(p)[c];
            s0 = fmaf(v.x, v.x, s0); s1 = fmaf(v.y, v.y, s1);
            s2 = fmaf(v.z, v.z, s2); s3 = fmaf(v.w, v.w, s3);
        }
        const float s = (s0 + s1) + (s2 + s3);
        if (t < 128) xq[r] = s; else yq[r] = s;
    }
    __syncthreads();

    // ---- per-wave 64x32 quadrant: 2 tiles of 32x32 (m), 1 tile (n) ----
    const int w = t >> 6;
    const int l = t & 63;
    const int mt0 = (w >> 2) * 2;   // 0 or 2
    const int nt  = w & 3;          // 0..3

    f32x16 acc0, acc1;
    #pragma unroll
    for (int r = 0; r < 16; ++r) { acc0[r] = 0.f; acc1[r] = 0.f; }

    #pragma unroll
    for (int ks = 0; ks < 4; ++ks) {
        const bf16x8 bh  = *reinterpret_cast<const bf16x8*>(&YfH[nt][ks][l][0]);
        const bf16x8 bl  = *reinterpret_cast<const bf16x8*>(&YfL[nt][ks][l][0]);
        const bf16x8 a0h = *reinterpret_cast<const bf16x8*>(&XfH[mt0 + 0][ks][l][0]);
        const bf16x8 a0l = *reinterpret_cast<const bf16x8*>(&XfL[mt0 + 0][ks][l][0]);
        const bf16x8 a1h = *reinterpret_cast<const bf16x8*>(&XfH[mt0 + 1][ks][l][0]);
        const bf16x8 a1l = *reinterpret_cast<const bf16x8*>(&XfL[mt0 + 1][ks][l][0]);
        // Y passed FIRST: D[reg-formula = n][lane&31 = m]
        acc0 = MFMA(bh, a0h, acc0);
        acc1 = MFMA(bh, a1h, acc1);
        acc0 = MFMA(bl, a0h, acc0);
        acc1 = MFMA(bl, a1h, acc1);
        acc0 = MFMA(bh, a0l, acc0);
        acc1 = MFMA(bh, a1l, acc1);
    }

    // ---- epilogue ----
    // lane l, reg r of acc_i: m = (mt0+i)*32 + (l&31),
    //                         n = nt*32 + (r&3) + 8*(r>>2) + 4*(l>>5)
    const float g  = gamma_p[0];
    const float g2 = 2.0f * g;
    const int   ln = l & 31;
    const int   nb0 = nt * 32 + 4 * (l >> 5);

    #pragma unroll
    for (int i = 0; i < 2; ++i) {
        const f32x16& acc = (i == 0) ? acc0 : acc1;
        const int  m    = (mt0 + i) * 32 + ln;
        const float ngx = -g * xq[m];
        float* orow = out + (row0 + m) * NTOT + col0 + nb0;
        #pragma unroll
        for (int q = 0; q < 4; ++q) {
            const float4 yv = *reinterpret_cast<const float4*>(&yq[nb0 + 8 * q]);
            float e[4];
            #pragma unroll
            for (int j = 0; j < 4; ++j) {
                // arg = -g*(xq + yq - 2*acc), clamped to <= 0  (s >= 0)
                float arg = fmaf(g2, acc[4 * q + j], fmaf(-g, ((const float*)&yv)[j], ngx));
                arg = fminf(arg, 0.f);
                e[j] = __expf(arg);
            }
            *reinterpret_cast<float4*>(orow + 8 * q) = make_float4(e[0], e[1], e[2], e[3]);
        }
    }
}

extern "C" void kernel_launch(void* const* d_in, const int* in_sizes, int n_in,
                              void* d_out, int out_size, void* d_ws, size_t ws_size,
                              hipStream_t stream) {
    (void)in_sizes; (void)n_in; (void)d_ws; (void)ws_size; (void)out_size;
    const float* X = (const float*)d_in[0];
    const float* Y = (const float*)d_in[1];
    const float* gamma_p = (const float*)d_in[2];
    float* out = (float*)d_out;

    dim3 grid(NTOT / 128, MTOT / 128);  // (64, 64)
    dim3 block(512);
    rbf_mfma_kernel<<<grid, block, 0, stream>>>(X, Y, gamma_p, out);
}